// Round 16
// baseline (30.426 us; speedup 1.0000x reference)
//
#include <hip/hip_runtime.h>

#define NPTS 2048
#define CCH  256

// ws byte layout:
//   [0    .. 4095 ]  W_eff (256x3 f32) + b_eff (256 f32)
//   [4096 .. 6143 ]  starts: per batch 128 u32 slots (65 used)
//   [8192 .. 139263] scrd: float4[4][2048] cell-sorted (x,y,z,orig_idx_bits)
#define STARTS_OFF 4096
#define CRD_OFF    8192

// ---- DPP cross-lane helpers ----
template <int CTRL>
__device__ __forceinline__ float dppf(float v) {
    return __int_as_float(__builtin_amdgcn_update_dpp(
        0, __float_as_int(v), CTRL, 0xF, 0xF, true));
}
__device__ __forceinline__ float row16_max(float v) {
    v = fmaxf(v, dppf<0xB1>(v));
    v = fmaxf(v, dppf<0x4E>(v));
    v = fmaxf(v, dppf<0x141>(v));
    v = fmaxf(v, dppf<0x140>(v));
    return v;
}
__device__ __forceinline__ float row16_sum(float v) {
    v += dppf<0xB1>(v);
    v += dppf<0x4E>(v);
    v += dppf<0x141>(v);
    v += dppf<0x140>(v);
    return v;
}
__device__ __forceinline__ float wave_sum(float v) {
    v = row16_sum(v);
    v += __shfl_xor(v, 16, 64);
    v += __shfl_xor(v, 32, 64);
    return v;
}
__device__ __forceinline__ int cell_coord(float v) {
    int c = (int)(v * 4.0f);
    return min(3, max(0, c));
}

// ---------------------------------------------------------------------------
// Fused prep + per-batch counting sort. Weight role: 4 output rows per block
// (64 blocks; W2 L2 traffic 16 MB). Sort role: unchanged.
// ---------------------------------------------------------------------------
__global__ __launch_bounds__(256) void prep_sort_kernel(
    const float* __restrict__ x,
    const float* __restrict__ w1, const float* __restrict__ b1,
    const float* __restrict__ w2, const float* __restrict__ b2,
    const float* __restrict__ w3, const float* __restrict__ b3,
    float* __restrict__ ws, int Bp)
{
    __shared__ float  w3row[4][CCH];
    __shared__ float4 wpart[4][4];
    __shared__ unsigned shist[64];
    __shared__ unsigned scur[64];

    int tid = threadIdx.x;

    if ((int)blockIdx.x < CCH / 4) {
        int o0 = blockIdx.x * 4, c = tid;
        float w3c[4];
#pragma unroll
        for (int r = 0; r < 4; ++r) {
            w3c[r] = w3[(o0 + r) * CCH + c];       // coalesced
            w3row[r][c] = w3c[r];
        }
        __syncthreads();

        float acc[4] = {0.f, 0.f, 0.f, 0.f};
        const float* w2c = w2 + c;
        for (int k = 0; k < CCH; k += 2) {
            float q0 = w2c[(k + 0) * CCH];
            float q1 = w2c[(k + 1) * CCH];
#pragma unroll
            for (int r = 0; r < 4; ++r) {
                acc[r] = fmaf(w3row[r][k + 0], q0, acc[r]);
                acc[r] = fmaf(w3row[r][k + 1], q1, acc[r]);
            }
        }

        float w1x = w1[c * 3 + 0], w1y = w1[c * 3 + 1], w1z = w1[c * 3 + 2];
        float b1c = b1[c], b2c = b2[c];

#pragma unroll
        for (int r = 0; r < 4; ++r) {
            float4 v = make_float4(acc[r] * w1x, acc[r] * w1y, acc[r] * w1z,
                                   fmaf(acc[r], b1c, w3c[r] * b2c));
            v.x = wave_sum(v.x); v.y = wave_sum(v.y);
            v.z = wave_sum(v.z); v.w = wave_sum(v.w);
            if ((c & 63) == 0) wpart[r][c >> 6] = v;
        }
        __syncthreads();
        if (c < 4) {
            int o = o0 + c;
            float4 p0 = wpart[c][0], p1 = wpart[c][1], p2 = wpart[c][2], p3 = wpart[c][3];
            ws[o * 3 + 0] = (p0.x + p1.x) + (p2.x + p3.x);
            ws[o * 3 + 1] = (p0.y + p1.y) + (p2.y + p3.y);
            ws[o * 3 + 2] = (p0.z + p1.z) + (p2.z + p3.z);
            ws[3 * CCH + o] = (p0.w + p1.w) + (p2.w + p3.w) + b3[o];
        }
        return;
    }

    int b = blockIdx.x - CCH / 4;
    if (b >= Bp) return;
    const float* xb = x + (size_t)b * NPTS * 3;

    if (tid < 64) shist[tid] = 0;
    __syncthreads();

    float a[24];
#pragma unroll
    for (int j = 0; j < 6; ++j)
        *(float4*)(a + 4 * j) = ((const float4*)xb)[tid * 6 + j];

    int cl[8];
#pragma unroll
    for (int k = 0; k < 8; ++k) {
        cl[k] = (cell_coord(a[3 * k + 0]) << 4) |
                (cell_coord(a[3 * k + 1]) << 2) |
                 cell_coord(a[3 * k + 2]);
        atomicAdd(&shist[cl[k]], 1u);
    }
    __syncthreads();

    unsigned* stg = (unsigned*)((char*)ws + STARTS_OFF) + b * 128;
    if (tid < 64) {
        unsigned v = shist[tid];
        unsigned incl = v;
#pragma unroll
        for (int s = 1; s < 64; s <<= 1) {
            unsigned o = __shfl_up(incl, s, 64);
            if (tid >= s) incl += o;
        }
        unsigned excl = incl - v;
        scur[tid] = excl;
        stg[tid] = excl;
        if (tid == 63) stg[64] = NPTS;
    }
    __syncthreads();

    float4* crd = (float4*)((char*)ws + CRD_OFF) + (size_t)b * NPTS;
#pragma unroll
    for (int k = 0; k < 8; ++k) {
        unsigned pos = atomicAdd(&scur[cl[k]], 1u);
        crd[pos] = make_float4(a[3 * k + 0], a[3 * k + 1], a[3 * k + 2],
                               __uint_as_float((unsigned)(8 * tid + k)));
    }
}

// ---------------------------------------------------------------------------
// pointsift v16: 4 POINTS PER WAVE (sorted-adjacent -> shared neighborhood).
// 256 threads = 4 waves = 16 points/block; 512 blocks (batch = blk&3).
// One candidate load feeds 4 independent d2/update chains (4x ILP per load,
// 4x fewer scan loads/iterations per CU). Union slab bounds cover every
// point's 27-cell window; extras are d2-filtered exactly. Selection:
// filtered ds_min_u64 on per-(wave,point,octant) slots with
// key=(d2_bits<<32)|orig_idx -> order-independent, numpy-first-min exact.
// ---------------------------------------------------------------------------
__global__ __launch_bounds__(256) void pointsift_kernel(
    const float* __restrict__ x,
    const float* __restrict__ ws,
    float* __restrict__ out)
{
    __shared__ unsigned sstart[65];
    __shared__ unsigned long long soct[4][4][8];   // [wave][pt][oct], 1 KB

    int tid = threadIdx.x;
    int batch = blockIdx.x & 3;
    int wave = tid >> 6;
    int lane = tid & 63;
    int p0 = (blockIdx.x >> 2) * 16 + wave * 4;    // sorted-position base

    const float* xb = x + (size_t)batch * NPTS * 3;
    const float4* crd = (const float4*)((const char*)ws + CRD_OFF) + (size_t)batch * NPTS;
    const unsigned* stg = (const unsigned*)((const char*)ws + STARTS_OFF) + batch * 128;

    if (tid < 65) sstart[tid] = stg[tid];

    // 4 centroids from the sorted array (wave-uniform broadcast loads)
    float4 c4[4];
    unsigned n_[4];
#pragma unroll
    for (int i = 0; i < 4; ++i) {
        c4[i] = crd[p0 + i];
        n_[i] = __float_as_uint(c4[i].w);          // original index
    }

    if (lane < 8) {
#pragma unroll
        for (int i = 0; i < 4; ++i)
            soct[wave][i][lane] = (0x7f800000ULL << 32) | n_[i];  // (inf, self)
    }

    // hoisted epilogue weight/bias loads
    const float4* wsv = (const float4*)ws;
    float4 wa = wsv[lane * 3 + 0];
    float4 wb = wsv[lane * 3 + 1];
    float4 wc = wsv[lane * 3 + 2];
    float4 be = ((const float4*)(ws + 3 * CCH))[lane];

    __syncthreads();                               // sstart visible

    // union slab bounds over the 4 points (each point's window covered)
    int alo = 3, ahi = 0, blo = 3, bhi = 0;
#pragma unroll
    for (int i = 0; i < 4; ++i) {
        int cxl = cell_coord(c4[i].x), cyl = cell_coord(c4[i].y);
        alo = min(alo, cxl > 0 ? cxl - 1 : 0);
        ahi = max(ahi, cxl < 3 ? cxl + 1 : 3);
        blo = min(blo, cyl > 0 ? cyl - 1 : 0);
        bhi = max(bhi, cyl < 3 ? cyl + 1 : 3);
    }

    for (int a = alo; a <= ahi; ++a) {
        unsigned s0 = sstart[(a << 4) | (blo << 2)];
        unsigned e0 = sstart[(a << 4) + (bhi << 2) + 4];
        for (unsigned pp = s0 + lane; pp < e0; pp += 64) {
            float4 p = crd[pp];
            unsigned midx = __float_as_uint(p.w);
#pragma unroll
            for (int i = 0; i < 4; ++i) {
                float dx = p.x - c4[i].x, dy = p.y - c4[i].y, dz = p.z - c4[i].z;
                // bit-match numpy: (dx*dx + dy*dy) + dz*dz, no FMA contraction
                float d2 = __fadd_rn(__fadd_rn(__fmul_rn(dx, dx), __fmul_rn(dy, dy)),
                                     __fmul_rn(dz, dz));
                if ((d2 > 1e-10f) && (d2 < 0.0625f)) {
                    // exact octant per reference: trunc(d+1.0) in {0,1}
                    int oct = 4 * (int)(dx + 1.0f) + 2 * (int)(dy + 1.0f) + (int)(dz + 1.0f);
                    unsigned long long key =
                        ((unsigned long long)__float_as_uint(d2) << 32) | midx;
                    unsigned long long cur =
                        __hip_atomic_load(&soct[wave][i][oct], __ATOMIC_RELAXED,
                                          __HIP_MEMORY_SCOPE_WORKGROUP);
                    if (key < cur)
                        __hip_atomic_fetch_min(&soct[wave][i][oct], key,
                                               __ATOMIC_RELAXED,
                                               __HIP_MEMORY_SCOPE_WORKGROUP);
                }
            }
        }
    }

    float w[4][3] = {{wa.x, wa.y, wa.z}, {wa.w, wb.x, wb.y},
                     {wb.z, wb.w, wc.x}, {wc.y, wc.z, wc.w}};
    float bev[4] = {be.x, be.y, be.z, be.w};

    // epilogue x4 points (same-wave DS ordering: soct reads are safe)
#pragma unroll
    for (int i = 0; i < 4; ++i) {
        int nidx[8];
#pragma unroll
        for (int k = 0; k < 8; ++k)
            nidx[k] = (int)(unsigned)soct[wave][i][k];

        float m16[4];
#pragma unroll
        for (int q = 0; q < 4; ++q) m16[q] = -__builtin_inff();
#pragma unroll
        for (int k = 0; k < 8; ++k) {
            float3 p = *(const float3*)(xb + 3 * nidx[k]);  // wave-uniform L1
            float gx = p.x - c4[i].x, gy = p.y - c4[i].y, gz = p.z - c4[i].z;
#pragma unroll
            for (int q = 0; q < 4; ++q) {
                float h = fmaf(gx, w[q][0], fmaf(gy, w[q][1], fmaf(gz, w[q][2], bev[q])));
                m16[k >> 1] = fmaxf(m16[k >> 1], h);
            }
        }

        float t[4], u[4];
#pragma unroll
        for (int q = 0; q < 4; ++q) {
            m16[q] = row16_max(m16[q]);
            t[q] = fmaxf(m16[q], __shfl_xor(m16[q], 16, 64));
            u[q] = fmaxf(t[q], __shfl_xor(t[q], 32, 64));
        }

        float* op = out + ((size_t)batch * NPTS + n_[i]) * 21;
        if ((lane & 15) == 0) {
            int j = lane >> 4;
#pragma unroll
            for (int q = 0; q < 4; ++q)
                op[q * 4 + j] = m16[q];
        }
        if (lane == 0 || lane == 32) {
            int j2 = lane >> 5;
            op[16 + 0 * 2 + j2] = fmaxf(t[0], t[1]);
            op[16 + 1 * 2 + j2] = fmaxf(t[2], t[3]);
        }
        if (lane == 0) {
            op[20] = fmaxf(fmaxf(u[0], u[1]), fmaxf(u[2], u[3]));
        }
    }
}

extern "C" void kernel_launch(void* const* d_in, const int* in_sizes, int n_in,
                              void* d_out, int out_size, void* d_ws, size_t ws_size,
                              hipStream_t stream) {
    const float* x  = (const float*)d_in[0];
    const float* w1 = (const float*)d_in[1];
    const float* b1 = (const float*)d_in[2];
    const float* w2 = (const float*)d_in[3];
    const float* b2 = (const float*)d_in[4];
    const float* w3 = (const float*)d_in[5];
    const float* b3 = (const float*)d_in[6];
    float* out = (float*)d_out;
    float* ws  = (float*)d_ws;

    int Bp = in_sizes[0] / (NPTS * 3);             // B*T = 4

    prep_sort_kernel<<<CCH / 4 + Bp, CCH, 0, stream>>>(
        x, w1, b1, w2, b2, w3, b3, ws, Bp);
    pointsift_kernel<<<Bp * (NPTS / 16), 256, 0, stream>>>(x, ws, out);
}

// Round 17
// 22.100 us; speedup vs baseline: 1.3768x; 1.3768x over previous
//
#include <hip/hip_runtime.h>

#define NPTS 2048
#define CCH  256

// ---- DPP cross-lane helpers (VALU pipe, no LDS) ----
template <int CTRL>
__device__ __forceinline__ float dppf(float v) {
    return __int_as_float(__builtin_amdgcn_update_dpp(
        0, __float_as_int(v), CTRL, 0xF, 0xF, true));
}
__device__ __forceinline__ float row16_max(float v) {
    v = fmaxf(v, dppf<0xB1>(v));
    v = fmaxf(v, dppf<0x4E>(v));
    v = fmaxf(v, dppf<0x141>(v));
    v = fmaxf(v, dppf<0x140>(v));
    return v;
}
__device__ __forceinline__ float row16_sum(float v) {
    v += dppf<0xB1>(v);
    v += dppf<0x4E>(v);
    v += dppf<0x141>(v);
    v += dppf<0x140>(v);
    return v;
}
__device__ __forceinline__ float wave_sum(float v) {
    v = row16_sum(v);
    v += __shfl_xor(v, 16, 64);
    v += __shfl_xor(v, 32, 64);
    return v;
}

__device__ __forceinline__ int cell_coord(float v) {
    int c = (int)(v * 4.0f);
    return min(3, max(0, c));
}

// ws layout (floats): [0..767] W_eff (256x3 row-major), [768..1023] b_eff

// ---------------------------------------------------------------------------
// Merged prep, 2 output rows per block (128 blocks): W2 L2 traffic halved.
// W_eff = (W3*W2)*W1, b_eff = (W3*W2)*b1 + W3*b2 + b3 (weights-only reassoc).
// ---------------------------------------------------------------------------
__global__ __launch_bounds__(256) void prep_kernel(
    const float* __restrict__ w1, const float* __restrict__ b1,
    const float* __restrict__ w2, const float* __restrict__ b2,
    const float* __restrict__ w3, const float* __restrict__ b3,
    float* __restrict__ ws)
{
    __shared__ float  w3row[2][CCH];
    __shared__ float4 wpart[2][4];
    int o0 = blockIdx.x * 2, c = threadIdx.x;

    float w3c0 = w3[(o0 + 0) * CCH + c];           // coalesced
    float w3c1 = w3[(o0 + 1) * CCH + c];
    w3row[0][c] = w3c0;
    w3row[1][c] = w3c1;
    __syncthreads();

    float a0 = 0.f, a1 = 0.f, a2 = 0.f, a3 = 0.f;    // row 0 partials
    float b0 = 0.f, b1p = 0.f, b2p = 0.f, b3p = 0.f; // row 1 partials
    const float* w2c = w2 + c;
    for (int k = 0; k < CCH; k += 4) {
        float q0 = w2c[(k + 0) * CCH];
        float q1 = w2c[(k + 1) * CCH];
        float q2 = w2c[(k + 2) * CCH];
        float q3 = w2c[(k + 3) * CCH];
        a0 = fmaf(w3row[0][k + 0], q0, a0);
        a1 = fmaf(w3row[0][k + 1], q1, a1);
        a2 = fmaf(w3row[0][k + 2], q2, a2);
        a3 = fmaf(w3row[0][k + 3], q3, a3);
        b0  = fmaf(w3row[1][k + 0], q0, b0);
        b1p = fmaf(w3row[1][k + 1], q1, b1p);
        b2p = fmaf(w3row[1][k + 2], q2, b2p);
        b3p = fmaf(w3row[1][k + 3], q3, b3p);
    }
    float accA = (a0 + a1) + (a2 + a3);            // M[o0][c]
    float accB = (b0 + b1p) + (b2p + b3p);         // M[o0+1][c]

    float w1x = w1[c * 3 + 0], w1y = w1[c * 3 + 1], w1z = w1[c * 3 + 2];
    float b1c = b1[c], b2c = b2[c];

    float4 vA = make_float4(accA * w1x, accA * w1y, accA * w1z,
                            fmaf(accA, b1c, w3c0 * b2c));
    float4 vB = make_float4(accB * w1x, accB * w1y, accB * w1z,
                            fmaf(accB, b1c, w3c1 * b2c));
    vA.x = wave_sum(vA.x); vA.y = wave_sum(vA.y);
    vA.z = wave_sum(vA.z); vA.w = wave_sum(vA.w);
    vB.x = wave_sum(vB.x); vB.y = wave_sum(vB.y);
    vB.z = wave_sum(vB.z); vB.w = wave_sum(vB.w);
    if ((c & 63) == 0) {
        wpart[0][c >> 6] = vA;
        wpart[1][c >> 6] = vB;
    }
    __syncthreads();
    if (c < 2) {
        int o = o0 + c;
        float4 p0 = wpart[c][0], p1 = wpart[c][1], p2 = wpart[c][2], p3 = wpart[c][3];
        ws[o * 3 + 0] = (p0.x + p1.x) + (p2.x + p3.x);
        ws[o * 3 + 1] = (p0.y + p1.y) + (p2.y + p3.y);
        ws[o * 3 + 2] = (p0.z + p1.z) + (p2.z + p3.z);
        ws[3 * CCH + o] = (p0.w + p1.w) + (p2.w + p3.w) + b3[o];
    }
}

// ---------------------------------------------------------------------------
// pointsift: 1024 threads = 16 waves = 16 points/block (R11, best measured).
// Phase A: in-block counting sort into 64 cells (4x4x4, cell width = radius).
// Phase B: fused pass over the 9 contiguous cell-runs of the 27-cell
//   neighborhood (~500 candidates). Each VALID candidate issues ONE
//   ds_min_u64 on its octant's per-wave slot, key = (d2_bits<<32)|orig_idx.
//   Min is associative/commutative -> scatter order can't leak; d2-ties
//   resolve to min original index (numpy first-min); valid => oct in [0,7].
//   Empty octant keeps init (inf, self) -> grouped = 0.
// ---------------------------------------------------------------------------
__global__ __launch_bounds__(1024) void pointsift_kernel(
    const float* __restrict__ x,   // [Bp, NPTS, 3]
    const float* __restrict__ ws,  // W_eff[256*3] then b_eff[256]
    float* __restrict__ out)       // [Bp, NPTS, 21]
{
    __shared__ float4 scrd[NPTS];                  // sorted (x,y,z,idx_bits) 32 KB
    __shared__ unsigned sstart[66];
    __shared__ unsigned shist[64];
    __shared__ unsigned scur[64];
    __shared__ unsigned long long soct[16][8];     // per-wave octant min slots 1 KB

    int tid = threadIdx.x;
    int batch = blockIdx.x >> 7;                   // 128 blocks per batch
    int n0    = (blockIdx.x & 127) * 16;
    const float* xb = x + (size_t)batch * NPTS * 3;

    // ---- phase A: histogram (2 points/thread, coalesced 24B) ----
    if (tid < 64) shist[tid] = 0;
    __syncthreads();

    float2 f0 = *(const float2*)(xb + 6 * tid + 0);
    float2 f1 = *(const float2*)(xb + 6 * tid + 2);
    float2 f2 = *(const float2*)(xb + 6 * tid + 4);
    float3 p0 = make_float3(f0.x, f0.y, f1.x);
    float3 p1 = make_float3(f1.y, f2.x, f2.y);
    int c0 = (cell_coord(p0.x) << 4) | (cell_coord(p0.y) << 2) | cell_coord(p0.z);
    int c1 = (cell_coord(p1.x) << 4) | (cell_coord(p1.y) << 2) | cell_coord(p1.z);
    atomicAdd(&shist[c0], 1u);
    atomicAdd(&shist[c1], 1u);
    __syncthreads();

    // wave 0: exclusive prefix scan of 64 cells
    if (tid < 64) {
        unsigned v = shist[tid];
        unsigned incl = v;
#pragma unroll
        for (int s = 1; s < 64; s <<= 1) {
            unsigned o = __shfl_up(incl, s, 64);
            if (tid >= s) incl += o;
        }
        unsigned excl = incl - v;
        sstart[tid] = excl;
        scur[tid] = excl;
        if (tid == 63) sstart[64] = NPTS;
    }
    __syncthreads();

    // scatter (within-cell order nondeterministic -> selection is lex-min, safe)
    {
        unsigned q0 = atomicAdd(&scur[c0], 1u);
        scrd[q0] = make_float4(p0.x, p0.y, p0.z, __uint_as_float(2u * tid));
        unsigned q1 = atomicAdd(&scur[c1], 1u);
        scrd[q1] = make_float4(p1.x, p1.y, p1.z, __uint_as_float(2u * tid + 1u));
    }

    int wave = tid >> 6;
    int lane = tid & 63;
    int n = n0 + wave;

    float3 cpt = *(const float3*)(xb + 3 * n);
    float cx = cpt.x, cy = cpt.y, cz = cpt.z;

    // init this wave's 8 octant slots: (inf, self). Same-wave DS ordering
    // guarantees init -> atomics -> readback without a barrier.
    if (lane < 8)
        soct[wave][lane] = (0x7f800000ULL << 32) | (unsigned)n;

    __syncthreads();                               // sorted arrays ready

    int ccx = cell_coord(cx), ccy = cell_coord(cy), ccz = cell_coord(cz);
    int zlo = ccz > 0 ? ccz - 1 : 0;
    int zhi = ccz < 3 ? ccz + 1 : 3;

    // ---- phase B: fused scan + octant lex-min via ds_min_u64 ----
    for (int di = -1; di <= 1; ++di) {
        int a = ccx + di;
        if ((unsigned)a > 3u) continue;
        for (int dj = -1; dj <= 1; ++dj) {
            int bc = ccy + dj;
            if ((unsigned)bc > 3u) continue;
            int base = (a << 4) | (bc << 2);
            unsigned s0 = sstart[base + zlo];
            unsigned e0 = sstart[base + zhi + 1];
            for (unsigned pp = s0 + lane; pp < e0; pp += 64) {
                float4 p = scrd[pp];
                float dx = p.x - cx, dy = p.y - cy, dz = p.z - cz;
                // bit-match numpy: (dx*dx + dy*dy) + dz*dz, no FMA contraction
                float d2 = __fadd_rn(__fadd_rn(__fmul_rn(dx, dx), __fmul_rn(dy, dy)),
                                     __fmul_rn(dz, dz));
                if ((d2 > 1e-10f) && (d2 < 0.0625f)) {
                    // exact octant per reference: trunc(d+1.0) in {0,1}
                    int oct = 4 * (int)(dx + 1.0f) + 2 * (int)(dy + 1.0f) + (int)(dz + 1.0f);
                    unsigned long long key =
                        ((unsigned long long)__float_as_uint(d2) << 32) |
                        __float_as_uint(p.w);
                    __hip_atomic_fetch_min(&soct[wave][oct], key,
                                           __ATOMIC_RELAXED,
                                           __HIP_MEMORY_SCOPE_WORKGROUP);
                }
            }
        }
    }

    // ---- readback: low 32 bits of each slot = selected original index ----
    int nidx[8];
#pragma unroll
    for (int k = 0; k < 8; ++k)
        nidx[k] = (int)(unsigned)soct[wave][k];    // broadcast LDS reads

    // ---- fused affine + SPP: lane handles channels 4*lane..4*lane+3 ----
    const float4* wsv = (const float4*)ws;
    float4 wa = wsv[lane * 3 + 0];
    float4 wb = wsv[lane * 3 + 1];
    float4 wc = wsv[lane * 3 + 2];
    float4 be = ((const float4*)(ws + 3 * CCH))[lane];
    float w[4][3] = {{wa.x, wa.y, wa.z}, {wa.w, wb.x, wb.y},
                     {wb.z, wb.w, wc.x}, {wc.y, wc.z, wc.w}};
    float bev[4] = {be.x, be.y, be.z, be.w};

    float m16[4];
#pragma unroll
    for (int i = 0; i < 4; ++i) m16[i] = -__builtin_inff();
#pragma unroll
    for (int k = 0; k < 8; ++k) {
        float3 p = *(const float3*)(xb + 3 * nidx[k]);  // wave-uniform L1 read
        float gx = p.x - cx, gy = p.y - cy, gz = p.z - cz;
#pragma unroll
        for (int q = 0; q < 4; ++q) {
            float h = fmaf(gx, w[q][0], fmaf(gy, w[q][1], fmaf(gz, w[q][2], bev[q])));
            m16[k >> 1] = fmaxf(m16[k >> 1], h);
        }
    }

    float t[4], u[4];
#pragma unroll
    for (int i = 0; i < 4; ++i) {
        m16[i] = row16_max(m16[i]);
        t[i] = fmaxf(m16[i], __shfl_xor(m16[i], 16, 64));
        u[i] = fmaxf(t[i], __shfl_xor(t[i], 32, 64));
    }

    float* op = out + ((size_t)batch * NPTS + n) * 21;
    if ((lane & 15) == 0) {
        int j = lane >> 4;
#pragma unroll
        for (int i = 0; i < 4; ++i)
            op[i * 4 + j] = m16[i];
    }
    if (lane == 0 || lane == 32) {
        int j2 = lane >> 5;
        op[16 + 0 * 2 + j2] = fmaxf(t[0], t[1]);
        op[16 + 1 * 2 + j2] = fmaxf(t[2], t[3]);
    }
    if (lane == 0) {
        op[20] = fmaxf(fmaxf(u[0], u[1]), fmaxf(u[2], u[3]));
    }
}

extern "C" void kernel_launch(void* const* d_in, const int* in_sizes, int n_in,
                              void* d_out, int out_size, void* d_ws, size_t ws_size,
                              hipStream_t stream) {
    const float* x  = (const float*)d_in[0];
    const float* w1 = (const float*)d_in[1];
    const float* b1 = (const float*)d_in[2];
    const float* w2 = (const float*)d_in[3];
    const float* b2 = (const float*)d_in[4];
    const float* w3 = (const float*)d_in[5];
    const float* b3 = (const float*)d_in[6];
    float* out = (float*)d_out;
    float* ws  = (float*)d_ws;

    prep_kernel<<<CCH / 2, CCH, 0, stream>>>(w1, b1, w2, b2, w3, b3, ws);

    int Bp = in_sizes[0] / (NPTS * 3);             // B*T = 4
    pointsift_kernel<<<Bp * (NPTS / 16), 1024, 0, stream>>>(x, ws, out);
}

// Round 18
// 21.610 us; speedup vs baseline: 1.4080x; 1.0227x over previous
//
#include <hip/hip_runtime.h>

#define NPTS 2048
#define CCH  256

// ws byte layout:
//   [0    .. 4095 ]  W_eff (256x3 f32) + b_eff (256 f32)
//   [4096 .. 6143 ]  starts: per batch 128 u32 slots (65 used)
//   [8192 .. 139263] scrd: float4[4][2048] cell-sorted (x,y,z,orig_idx_bits)
#define STARTS_OFF 4096
#define CRD_OFF    8192

// ---- DPP cross-lane helpers ----
template <int CTRL>
__device__ __forceinline__ float dppf(float v) {
    return __int_as_float(__builtin_amdgcn_update_dpp(
        0, __float_as_int(v), CTRL, 0xF, 0xF, true));
}
__device__ __forceinline__ float row16_max(float v) {
    v = fmaxf(v, dppf<0xB1>(v));
    v = fmaxf(v, dppf<0x4E>(v));
    v = fmaxf(v, dppf<0x141>(v));
    v = fmaxf(v, dppf<0x140>(v));
    return v;
}
__device__ __forceinline__ float row16_sum(float v) {
    v += dppf<0xB1>(v);
    v += dppf<0x4E>(v);
    v += dppf<0x141>(v);
    v += dppf<0x140>(v);
    return v;
}
__device__ __forceinline__ float wave_sum(float v) {
    v = row16_sum(v);
    v += __shfl_xor(v, 16, 64);
    v += __shfl_xor(v, 32, 64);
    return v;
}
__device__ __forceinline__ int cell_coord(float v) {
    int c = (int)(v * 4.0f);
    return min(3, max(0, c));
}

// ---------------------------------------------------------------------------
// Fused prep + per-batch counting sort (R12 structure).
// Blocks 0..127: weight collapse (2 rows each). Blocks 128..131: sort batch
// into 64 cells, writing sorted float4s + run starts to ws. Sort role runs
// concurrently with weight role -> its cost is hidden.
// ---------------------------------------------------------------------------
__global__ __launch_bounds__(256) void prep_sort_kernel(
    const float* __restrict__ x,
    const float* __restrict__ w1, const float* __restrict__ b1,
    const float* __restrict__ w2, const float* __restrict__ b2,
    const float* __restrict__ w3, const float* __restrict__ b3,
    float* __restrict__ ws, int Bp)
{
    __shared__ float  w3row[2][CCH];
    __shared__ float4 wpart[2][4];
    __shared__ unsigned shist[64];
    __shared__ unsigned scur[64];

    int tid = threadIdx.x;

    if ((int)blockIdx.x < CCH / 2) {
        // ---- weight role: W_eff = (W3*W2)*W1 etc (weights-only reassoc) ----
        int o0 = blockIdx.x * 2, c = tid;
        float w3c0 = w3[(o0 + 0) * CCH + c];
        float w3c1 = w3[(o0 + 1) * CCH + c];
        w3row[0][c] = w3c0;
        w3row[1][c] = w3c1;
        __syncthreads();

        float a0 = 0.f, a1 = 0.f, a2 = 0.f, a3 = 0.f;
        float b0 = 0.f, b1p = 0.f, b2p = 0.f, b3p = 0.f;
        const float* w2c = w2 + c;
        for (int k = 0; k < CCH; k += 4) {
            float q0 = w2c[(k + 0) * CCH];
            float q1 = w2c[(k + 1) * CCH];
            float q2 = w2c[(k + 2) * CCH];
            float q3 = w2c[(k + 3) * CCH];
            a0 = fmaf(w3row[0][k + 0], q0, a0);
            a1 = fmaf(w3row[0][k + 1], q1, a1);
            a2 = fmaf(w3row[0][k + 2], q2, a2);
            a3 = fmaf(w3row[0][k + 3], q3, a3);
            b0  = fmaf(w3row[1][k + 0], q0, b0);
            b1p = fmaf(w3row[1][k + 1], q1, b1p);
            b2p = fmaf(w3row[1][k + 2], q2, b2p);
            b3p = fmaf(w3row[1][k + 3], q3, b3p);
        }
        float accA = (a0 + a1) + (a2 + a3);
        float accB = (b0 + b1p) + (b2p + b3p);

        float w1x = w1[c * 3 + 0], w1y = w1[c * 3 + 1], w1z = w1[c * 3 + 2];
        float b1c = b1[c], b2c = b2[c];

        float4 vA = make_float4(accA * w1x, accA * w1y, accA * w1z,
                                fmaf(accA, b1c, w3c0 * b2c));
        float4 vB = make_float4(accB * w1x, accB * w1y, accB * w1z,
                                fmaf(accB, b1c, w3c1 * b2c));
        vA.x = wave_sum(vA.x); vA.y = wave_sum(vA.y);
        vA.z = wave_sum(vA.z); vA.w = wave_sum(vA.w);
        vB.x = wave_sum(vB.x); vB.y = wave_sum(vB.y);
        vB.z = wave_sum(vB.z); vB.w = wave_sum(vB.w);
        if ((c & 63) == 0) {
            wpart[0][c >> 6] = vA;
            wpart[1][c >> 6] = vB;
        }
        __syncthreads();
        if (c < 2) {
            int o = o0 + c;
            float4 p0 = wpart[c][0], p1 = wpart[c][1], p2 = wpart[c][2], p3 = wpart[c][3];
            ws[o * 3 + 0] = (p0.x + p1.x) + (p2.x + p3.x);
            ws[o * 3 + 1] = (p0.y + p1.y) + (p2.y + p3.y);
            ws[o * 3 + 2] = (p0.z + p1.z) + (p2.z + p3.z);
            ws[3 * CCH + o] = (p0.w + p1.w) + (p2.w + p3.w) + b3[o];
        }
        return;
    }

    // ---- sort role: batch b, 8 points/thread ----
    int b = blockIdx.x - CCH / 2;
    if (b >= Bp) return;
    const float* xb = x + (size_t)b * NPTS * 3;

    if (tid < 64) shist[tid] = 0;
    __syncthreads();

    // 6 float4 loads = floats 24t..24t+23 = points 8t..8t+7
    float a[24];
#pragma unroll
    for (int j = 0; j < 6; ++j)
        *(float4*)(a + 4 * j) = ((const float4*)xb)[tid * 6 + j];

    int cl[8];
#pragma unroll
    for (int k = 0; k < 8; ++k) {
        cl[k] = (cell_coord(a[3 * k + 0]) << 4) |
                (cell_coord(a[3 * k + 1]) << 2) |
                 cell_coord(a[3 * k + 2]);
        atomicAdd(&shist[cl[k]], 1u);
    }
    __syncthreads();

    unsigned* stg = (unsigned*)((char*)ws + STARTS_OFF) + b * 128;
    if (tid < 64) {                     // wave 0: exclusive prefix scan
        unsigned v = shist[tid];
        unsigned incl = v;
#pragma unroll
        for (int s = 1; s < 64; s <<= 1) {
            unsigned o = __shfl_up(incl, s, 64);
            if (tid >= s) incl += o;
        }
        unsigned excl = incl - v;
        scur[tid] = excl;
        stg[tid] = excl;
        if (tid == 63) stg[64] = NPTS;
    }
    __syncthreads();

    float4* crd = (float4*)((char*)ws + CRD_OFF) + (size_t)b * NPTS;
#pragma unroll
    for (int k = 0; k < 8; ++k) {
        unsigned pos = atomicAdd(&scur[cl[k]], 1u);
        crd[pos] = make_float4(a[3 * k + 0], a[3 * k + 1], a[3 * k + 2],
                               __uint_as_float((unsigned)(8 * tid + k)));
    }
}

// ---------------------------------------------------------------------------
// pointsift: 1024 threads = 16 waves = 16 points/block (R11 scan/selection).
// Phase A REPLACED by a plain coalesced copy of the pre-sorted array into
// LDS (2x b128 per thread) -- no histogram, no prefix scan, no LDS-atomic
// scatter. Phase B + selection identical to the measured-best R11 kernel:
// 9 cell-runs, ONE ds_min_u64 per valid candidate, key=(d2_bits<<32)|idx.
// Lex-min selection => prep's nondeterministic within-cell order cannot
// affect the output; d2-ties resolve to min original index (numpy first-min).
// ---------------------------------------------------------------------------
__global__ __launch_bounds__(1024) void pointsift_kernel(
    const float* __restrict__ x,   // [Bp, NPTS, 3]
    const float* __restrict__ ws,
    float* __restrict__ out)       // [Bp, NPTS, 21]
{
    __shared__ float4 scrd[NPTS];                  // sorted (x,y,z,idx_bits) 32 KB
    __shared__ unsigned sstart[65];
    __shared__ unsigned long long soct[16][8];     // per-wave octant slots 1 KB

    int tid = threadIdx.x;
    int batch = blockIdx.x >> 7;                   // 128 blocks per batch
    int n0    = (blockIdx.x & 127) * 16;
    const float* xb = x + (size_t)batch * NPTS * 3;
    const float4* crd = (const float4*)((const char*)ws + CRD_OFF) + (size_t)batch * NPTS;
    const unsigned* stg = (const unsigned*)((const char*)ws + STARTS_OFF) + batch * 128;

    // ---- stage pre-sorted array into LDS (plain coalesced copy) ----
    scrd[tid]        = crd[tid];
    scrd[tid + 1024] = crd[tid + 1024];
    if (tid < 65) sstart[tid] = stg[tid];

    int wave = tid >> 6;
    int lane = tid & 63;
    int n = n0 + wave;

    float3 cpt = *(const float3*)(xb + 3 * n);     // original centroid coords
    float cx = cpt.x, cy = cpt.y, cz = cpt.z;

    // init this wave's 8 octant slots: (inf, self). Same-wave DS ordering
    // guarantees init -> atomics -> readback without a barrier.
    if (lane < 8)
        soct[wave][lane] = (0x7f800000ULL << 32) | (unsigned)n;

    __syncthreads();                               // scrd/sstart ready

    int ccx = cell_coord(cx), ccy = cell_coord(cy), ccz = cell_coord(cz);
    int zlo = ccz > 0 ? ccz - 1 : 0;
    int zhi = ccz < 3 ? ccz + 1 : 3;

    // ---- phase B: fused scan + octant lex-min via ds_min_u64 ----
    for (int di = -1; di <= 1; ++di) {
        int a = ccx + di;
        if ((unsigned)a > 3u) continue;
        for (int dj = -1; dj <= 1; ++dj) {
            int bc = ccy + dj;
            if ((unsigned)bc > 3u) continue;
            int base = (a << 4) | (bc << 2);
            unsigned s0 = sstart[base + zlo];
            unsigned e0 = sstart[base + zhi + 1];
            for (unsigned pp = s0 + lane; pp < e0; pp += 64) {
                float4 p = scrd[pp];
                float dx = p.x - cx, dy = p.y - cy, dz = p.z - cz;
                // bit-match numpy: (dx*dx + dy*dy) + dz*dz, no FMA contraction
                float d2 = __fadd_rn(__fadd_rn(__fmul_rn(dx, dx), __fmul_rn(dy, dy)),
                                     __fmul_rn(dz, dz));
                if ((d2 > 1e-10f) && (d2 < 0.0625f)) {
                    // exact octant per reference: trunc(d+1.0) in {0,1}
                    int oct = 4 * (int)(dx + 1.0f) + 2 * (int)(dy + 1.0f) + (int)(dz + 1.0f);
                    unsigned long long key =
                        ((unsigned long long)__float_as_uint(d2) << 32) |
                        __float_as_uint(p.w);
                    __hip_atomic_fetch_min(&soct[wave][oct], key,
                                           __ATOMIC_RELAXED,
                                           __HIP_MEMORY_SCOPE_WORKGROUP);
                }
            }
        }
    }

    // ---- readback: low 32 bits of each slot = selected original index ----
    int nidx[8];
#pragma unroll
    for (int k = 0; k < 8; ++k)
        nidx[k] = (int)(unsigned)soct[wave][k];    // broadcast LDS reads

    // ---- fused affine + SPP: lane handles channels 4*lane..4*lane+3 ----
    const float4* wsv = (const float4*)ws;
    float4 wa = wsv[lane * 3 + 0];
    float4 wb = wsv[lane * 3 + 1];
    float4 wc = wsv[lane * 3 + 2];
    float4 be = ((const float4*)(ws + 3 * CCH))[lane];
    float w[4][3] = {{wa.x, wa.y, wa.z}, {wa.w, wb.x, wb.y},
                     {wb.z, wb.w, wc.x}, {wc.y, wc.z, wc.w}};
    float bev[4] = {be.x, be.y, be.z, be.w};

    float m16[4];
#pragma unroll
    for (int i = 0; i < 4; ++i) m16[i] = -__builtin_inff();
#pragma unroll
    for (int k = 0; k < 8; ++k) {
        float3 p = *(const float3*)(xb + 3 * nidx[k]);  // wave-uniform L1 read
        float gx = p.x - cx, gy = p.y - cy, gz = p.z - cz;
#pragma unroll
        for (int q = 0; q < 4; ++q) {
            float h = fmaf(gx, w[q][0], fmaf(gy, w[q][1], fmaf(gz, w[q][2], bev[q])));
            m16[k >> 1] = fmaxf(m16[k >> 1], h);
        }
    }

    float t[4], u[4];
#pragma unroll
    for (int i = 0; i < 4; ++i) {
        m16[i] = row16_max(m16[i]);
        t[i] = fmaxf(m16[i], __shfl_xor(m16[i], 16, 64));
        u[i] = fmaxf(t[i], __shfl_xor(t[i], 32, 64));
    }

    float* op = out + ((size_t)batch * NPTS + n) * 21;
    if ((lane & 15) == 0) {
        int j = lane >> 4;
#pragma unroll
        for (int i = 0; i < 4; ++i)
            op[i * 4 + j] = m16[i];
    }
    if (lane == 0 || lane == 32) {
        int j2 = lane >> 5;
        op[16 + 0 * 2 + j2] = fmaxf(t[0], t[1]);
        op[16 + 1 * 2 + j2] = fmaxf(t[2], t[3]);
    }
    if (lane == 0) {
        op[20] = fmaxf(fmaxf(u[0], u[1]), fmaxf(u[2], u[3]));
    }
}

extern "C" void kernel_launch(void* const* d_in, const int* in_sizes, int n_in,
                              void* d_out, int out_size, void* d_ws, size_t ws_size,
                              hipStream_t stream) {
    const float* x  = (const float*)d_in[0];
    const float* w1 = (const float*)d_in[1];
    const float* b1 = (const float*)d_in[2];
    const float* w2 = (const float*)d_in[3];
    const float* b2 = (const float*)d_in[4];
    const float* w3 = (const float*)d_in[5];
    const float* b3 = (const float*)d_in[6];
    float* out = (float*)d_out;
    float* ws  = (float*)d_ws;

    int Bp = in_sizes[0] / (NPTS * 3);             // B*T = 4

    prep_sort_kernel<<<CCH / 2 + Bp, CCH, 0, stream>>>(
        x, w1, b1, w2, b2, w3, b3, ws, Bp);
    pointsift_kernel<<<Bp * (NPTS / 16), 1024, 0, stream>>>(x, ws, out);
}